// Round 16
// baseline (350.038 us; speedup 1.0000x reference)
//
#include <hip/hip_runtime.h>
#include <hip/hip_bf16.h>

#define N_NODE 100000
#define N_REL  8
#define EMB    32
#define OUT    32
#define N_BASIS 30
#define E_EDGE 1600000
#define BATCH  16384
#define H1 64
#define H2 32
#define H3 16
#define NEG_SLOPE 0.2f

#define BSH   8             // bucket = dst >> 8 (256 nodes/bucket)
#define NBKT  391           // ceil(100000/256)
#define BCAP  5120          // per-bucket slot capacity (mean 4092, +16 sigma)
#define PCH   2048          // edges per k_part block; 782 blocks (3/CU)

// x_ids = arange(N_NODE) by construction -> emb read directly (affine addresses).

// -------- K0f: w = weight@basis (also to LDS), wa = w·att halves, zero bcnt. 1 block.
__global__ __launch_bounds__(256) void k0f(const float* __restrict__ weight,
                                           const float* __restrict__ basis,
                                           const float* __restrict__ att,
                                           float* __restrict__ w,
                                           float* __restrict__ wa,
                                           unsigned* __restrict__ bcnt) {
    __shared__ float wl[N_REL * EMB * OUT];    // 32 KB
    int t = threadIdx.x;
    for (int i = t; i < N_REL * EMB * OUT; i += 256) {
        int r = i >> 10, fo = i & 1023;
        float acc = 0.f;
        #pragma unroll
        for (int b = 0; b < N_BASIS; b++)
            acc = fmaf(weight[r * N_BASIS + b], basis[b * (EMB * OUT) + fo], acc);
        wl[i] = acc;
        w[i] = acc;
    }
    __syncthreads();
    for (int i = t; i < 512; i += 256) {       // wa[which][r][f]
        int which = i >> 8, rf = i & 255, r = rf >> 5, f = rf & 31;
        const float* wrow = wl + (r * 32 + f) * 32;
        const float* arow = att + r * 64 + which * 32;
        float acc = 0.f;
        #pragma unroll
        for (int o = 0; o < 32; o++) acc = fmaf(wrow[o], arow[o], acc);
        wa[i] = acc;
    }
    for (int i = t; i < NBKT; i += 256) bcnt[i] = 0;
}

// -------- K1: xh = x@w in BF16. wc pinned in VGPRs via empty asm (VGPR_Count=20 last
// round proved the compiler was re-loading w inside the loop instead of keeping wc).
__global__ __launch_bounds__(256, 4) void k1_transform(const float* __restrict__ emb,
                                                       const float* __restrict__ w,
                                                       unsigned short* __restrict__ xh) {
    const int t = threadIdx.x;
    const int o = t & 31;
    const int r = t >> 5;

    float wc[EMB];
    #pragma unroll
    for (int f = 0; f < EMB; f++) wc[f] = w[(r * EMB + f) * OUT + o];
    #pragma unroll
    for (int f = 0; f < EMB; f++) asm volatile("" : "+v"(wc[f]));  // pin: no remat

    for (int n0 = blockIdx.x * 4; n0 < N_NODE; n0 += gridDim.x * 4) {
        const float* __restrict__ x0 = emb + (size_t)(n0 + 0) * EMB;
        const float* __restrict__ x1 = emb + (size_t)(n0 + 1) * EMB;
        const float* __restrict__ x2 = emb + (size_t)(n0 + 2) * EMB;
        const float* __restrict__ x3 = emb + (size_t)(n0 + 3) * EMB;

        float a0 = 0.f, a1 = 0.f, a2 = 0.f, a3 = 0.f;
        #pragma unroll
        for (int f = 0; f < EMB; f++) {      // 4 independent FMA chains; x via s_load
            a0 = fmaf(x0[f], wc[f], a0);
            a1 = fmaf(x1[f], wc[f], a1);
            a2 = fmaf(x2[f], wc[f], a2);
            a3 = fmaf(x3[f], wc[f], a3);
        }
        __hip_bfloat16 b0 = __float2bfloat16(a0);
        __hip_bfloat16 b1 = __float2bfloat16(a1);
        __hip_bfloat16 b2 = __float2bfloat16(a2);
        __hip_bfloat16 b3 = __float2bfloat16(a3);
        xh[(size_t)(n0 + 0) * 256 + t] = *(unsigned short*)&b0;
        xh[(size_t)(n0 + 1) * 256 + t] = *(unsigned short*)&b1;
        xh[(size_t)(n0 + 2) * 256 + t] = *(unsigned short*)&b2;
        xh[(size_t)(n0 + 3) * 256 + t] = *(unsigned short*)&b3;
    }
}

// -------- k_pi: fused agg-init + p_i/p_j. Thread per (n,o); emb row direct.
__global__ __launch_bounds__(256) void k_pi(const float* __restrict__ emb,
                                            const float* __restrict__ wa,
                                            const float* __restrict__ root,
                                            const float* __restrict__ bias,
                                            float* __restrict__ p_i,
                                            float* __restrict__ p_j,
                                            float* __restrict__ agg) {
    __shared__ float rs[EMB * OUT];            // [f*32+o]
    __shared__ float bs[OUT];
    __shared__ float wis[256], wjs[256];       // [f*8+r]
    int t = threadIdx.x;
    for (int i = t; i < EMB * OUT; i += 256) rs[i] = root[i];
    if (t < OUT) bs[t] = bias[t];
    for (int i = t; i < 512; i += 256) {
        int which = i >> 8, r = (i >> 5) & 7, f = i & 31;
        float v = wa[i];
        if (which == 0) wis[f * 8 + r] = v; else wjs[f * 8 + r] = v;
    }
    __syncthreads();
    int tg = blockIdx.x * 256 + t;             // grid*256 == 3,200,000 exactly
    int n = tg >> 5, o = tg & 31;
    const float4* xr4 = (const float4*)(emb + (size_t)n * EMB);
    float xf[EMB];
    #pragma unroll
    for (int c = 0; c < 8; c++) {
        float4 xv = xr4[c];
        xf[4 * c + 0] = xv.x; xf[4 * c + 1] = xv.y;
        xf[4 * c + 2] = xv.z; xf[4 * c + 3] = xv.w;
    }
    float a = bs[o];
    #pragma unroll
    for (int f = 0; f < EMB; f++) a = fmaf(xf[f], rs[f * 32 + o], a);
    agg[tg] = a;
    if (o < N_REL) {                           // lanes 0-7 / 32-39 also emit p for r=o
        float ai = 0.f, aj = 0.f;
        #pragma unroll
        for (int f = 0; f < EMB; f++) {
            ai = fmaf(xf[f], wis[f * 8 + o], ai);
            aj = fmaf(xf[f], wjs[f * 8 + o], aj);
        }
        p_i[n * N_REL + o] = ai;
        p_j[n * N_REL + o] = aj;
    }
}

// -------- k_part: vectorized single-pass edge loads (int4), values in registers
// across hist -> stage. Chunk sizes (2048 / 512 tail-block) are multiples of 4.
__global__ __launch_bounds__(256) void k_part(const int* __restrict__ src,
                                              const int* __restrict__ dst,
                                              const int* __restrict__ et,
                                              unsigned* __restrict__ bcnt,
                                              unsigned* __restrict__ part) {
    __shared__ unsigned long long stage[PCH];            // 16 KB
    __shared__ unsigned hist[NBKT], lbase[NBKT], lcur[NBKT], gbase[NBKT];
    __shared__ unsigned sc[256];
    int t = threadIdx.x;
    for (int i = t; i < NBKT; i += 256) hist[i] = 0;
    __syncthreads();
    int beg = blockIdx.x * PCH, end = min(beg + PCH, E_EDGE);
    int n = end - beg;                  // 2048 or 512: always multiple of 4
    int ng = n >> 2;                    // groups of 4 edges
    int g0 = t, g1 = t + 256;
    bool has0 = g0 < ng, has1 = g1 < ng;
    int4 s0v = {}, d0v = {}, e0v = {}, s1v = {}, d1v = {}, e1v = {};
    if (has0) {
        s0v = *(const int4*)&src[beg + 4 * g0];
        d0v = *(const int4*)&dst[beg + 4 * g0];
        e0v = *(const int4*)&et[beg + 4 * g0];
    }
    if (has1) {
        s1v = *(const int4*)&src[beg + 4 * g1];
        d1v = *(const int4*)&dst[beg + 4 * g1];
        e1v = *(const int4*)&et[beg + 4 * g1];
    }
    if (has0) {
        atomicAdd(&hist[(unsigned)d0v.x >> BSH], 1u);
        atomicAdd(&hist[(unsigned)d0v.y >> BSH], 1u);
        atomicAdd(&hist[(unsigned)d0v.z >> BSH], 1u);
        atomicAdd(&hist[(unsigned)d0v.w >> BSH], 1u);
    }
    if (has1) {
        atomicAdd(&hist[(unsigned)d1v.x >> BSH], 1u);
        atomicAdd(&hist[(unsigned)d1v.y >> BSH], 1u);
        atomicAdd(&hist[(unsigned)d1v.z >> BSH], 1u);
        atomicAdd(&hist[(unsigned)d1v.w >> BSH], 1u);
    }
    __syncthreads();
    // 512-wide scan with 256 threads (2 bins per thread)
    unsigned v0 = (2 * t < NBKT) ? hist[2 * t] : 0u;
    unsigned v1 = (2 * t + 1 < NBKT) ? hist[2 * t + 1] : 0u;
    unsigned s = v0 + v1;
    sc[t] = s;
    __syncthreads();
    for (int off = 1; off < 256; off <<= 1) {
        unsigned y = (t >= off) ? sc[t - off] : 0u;
        __syncthreads();
        sc[t] += y;
        __syncthreads();
    }
    unsigned ex = sc[t] - s;
    if (2 * t < NBKT)     { lbase[2 * t] = ex;          lcur[2 * t] = ex; }
    if (2 * t + 1 < NBKT) { lbase[2 * t + 1] = ex + v0; lcur[2 * t + 1] = ex + v0; }
    __syncthreads();
    #define K_PART_STAGE(dd, ss, ee) do {                                   \
        unsigned b_ = (unsigned)(dd) >> BSH;                                \
        unsigned ent_ = ((unsigned)((dd) & 255) << 20)                      \
                      | ((unsigned)(ss) << 3) | (unsigned)(ee);             \
        unsigned pos_ = atomicAdd(&lcur[b_], 1u);                           \
        stage[pos_] = ((unsigned long long)b_ << 32) | ent_; } while (0)
    if (has0) {
        K_PART_STAGE(d0v.x, s0v.x, e0v.x);
        K_PART_STAGE(d0v.y, s0v.y, e0v.y);
        K_PART_STAGE(d0v.z, s0v.z, e0v.z);
        K_PART_STAGE(d0v.w, s0v.w, e0v.w);
    }
    if (has1) {
        K_PART_STAGE(d1v.x, s1v.x, e1v.x);
        K_PART_STAGE(d1v.y, s1v.y, e1v.y);
        K_PART_STAGE(d1v.z, s1v.z, e1v.z);
        K_PART_STAGE(d1v.w, s1v.w, e1v.w);
    }
    #undef K_PART_STAGE
    __syncthreads();
    for (int i = t; i < NBKT; i += 256)
        if (hist[i]) gbase[i] = atomicAdd(&bcnt[i], hist[i]);
    __syncthreads();
    for (int i = t; i < n; i += 256) {
        unsigned long long s64 = stage[i];
        unsigned b = (unsigned)(s64 >> 32);
        unsigned ent = (unsigned)s64;
        part[b * BCAP + gbase[b] + (i - lbase[b])] = ent;   // contiguous runs
    }
}

// -------- k_sort: block per bucket (391); counting sort by dst-low (256 bins).
__global__ __launch_bounds__(256) void k_sort(const unsigned* __restrict__ bcnt,
                                              const unsigned* __restrict__ part,
                                              int* __restrict__ payload,
                                              int* __restrict__ begp,
                                              int* __restrict__ endp) {
    __shared__ unsigned ent[BCAP];             // 20 KB
    __shared__ unsigned ent2[BCAP];            // 20 KB
    __shared__ unsigned hist[256], dbase[256], dcur[256];
    __shared__ unsigned sc[256];
    int t = threadIdx.x;
    int b = blockIdx.x;
    unsigned s0 = (unsigned)b * BCAP;          // 4-aligned (BCAP%4==0)
    int n = (int)bcnt[b];
    if (n > BCAP) n = BCAP;                      // statistically unreachable
    hist[t] = 0;
    __syncthreads();
    int n4 = n & ~3;
    for (int i = 4 * t; i < n4; i += 1024) {   // vectorized slab read
        uint4 e4 = *(const uint4*)&part[s0 + i];
        ent[i + 0] = e4.x; atomicAdd(&hist[e4.x >> 20], 1u);
        ent[i + 1] = e4.y; atomicAdd(&hist[e4.y >> 20], 1u);
        ent[i + 2] = e4.z; atomicAdd(&hist[e4.z >> 20], 1u);
        ent[i + 3] = e4.w; atomicAdd(&hist[e4.w >> 20], 1u);
    }
    for (int i = n4 + t; i < n; i += 256) {    // tail
        unsigned e = part[s0 + i];
        ent[i] = e;
        atomicAdd(&hist[e >> 20], 1u);
    }
    __syncthreads();
    unsigned v = hist[t];
    sc[t] = v;
    __syncthreads();
    for (int off = 1; off < 256; off <<= 1) {
        unsigned y = (t >= off) ? sc[t - off] : 0u;
        __syncthreads();
        sc[t] += y;
        __syncthreads();
    }
    unsigned ex = sc[t] - v;
    dbase[t] = ex;
    dcur[t] = ex;
    __syncthreads();
    int d = (b << BSH) + t;                      // one node per thread
    if (d < N_NODE) {
        begp[d] = (int)(s0 + dbase[t]);
        endp[d] = (int)(s0 + dbase[t] + hist[t]);
    }
    for (int i = t; i < n; i += 256) {
        unsigned e = ent[i];
        unsigned pos = atomicAdd(&dcur[e >> 20], 1u);
        ent2[pos] = e & 0xFFFFFu;                // sr = (src<<3)|rel
    }
    __syncthreads();
    for (int i = 4 * t; i < n4; i += 1024) {   // vectorized payload write
        uint4 o4 = { ent2[i + 0], ent2[i + 1], ent2[i + 2], ent2[i + 3] };
        *(uint4*)&payload[s0 + i] = o4;
    }
    for (int i = n4 + t; i < n; i += 256) payload[s0 + i] = (int)ent2[i];
}

// ------------- k_agg: wave per dst, over d-range [d0,d1). bf16 xh rows.
__global__ __launch_bounds__(256) void k_agg(const int* __restrict__ begp,
                                             const int* __restrict__ endp,
                                             const int* __restrict__ payload,
                                             const float* __restrict__ p_i,
                                             const float* __restrict__ p_j,
                                             const unsigned short* __restrict__ xh,
                                             float* __restrict__ agg,
                                             int d0, int d1) {
    int d = d0 + blockIdx.x * 4 + (threadIdx.x >> 6);
    if (d >= d1) return;
    const int lane = threadIdx.x & 63;
    const int h = lane >> 5;          // half-wave id
    const int o = lane & 31;          // output component
    const int beg = begp[d], end = endp[d];
    const int cnt = end - beg;
    if (cnt == 0) return;

    float pid[8];                     // d wave-uniform -> scalar loads
    #pragma unroll
    for (int k = 0; k < 8; k++) pid[k] = p_i[(d << 3) | k];

    if (cnt <= 64) {
        int sr = 0, r = 0; float ev = 0.f;
        if (lane < cnt) {
            sr = payload[beg + lane];
            r = sr & 7;
            float pi = pid[0];
            #pragma unroll
            for (int k = 1; k < 8; k++) pi = (r == k) ? pid[k] : pi;
            float a = pi + p_j[sr];
            a = (a >= 0.f) ? a : NEG_SLOPE * a;
            ev = __expf(a);
        }
        float sex[8];
        #pragma unroll
        for (int k = 0; k < 8; k++) sex[k] = (r == k) ? ev : 0.f;
        #pragma unroll
        for (int k = 0; k < 8; k++) {
            #pragma unroll
            for (int m = 1; m <= 32; m <<= 1) sex[k] += __shfl_xor(sex[k], m, 64);
        }
        float de = sex[0];
        #pragma unroll
        for (int k = 1; k < 8; k++) de = (r == k) ? sex[k] : de;
        float al = ev / (de + 1e-16f);           // inactive lanes: al = 0

        float w0 = 0.f, w1 = 0.f, w2 = 0.f, w3 = 0.f;
        for (int j0 = 0; j0 < cnt; j0 += 8) {
            float b0 = __shfl(al, j0 + h,     64);
            float b1 = __shfl(al, j0 + 2 + h, 64);
            float b2 = __shfl(al, j0 + 4 + h, 64);
            float b3 = __shfl(al, j0 + 6 + h, 64);
            int t0 = payload[beg + j0 + h]     & 0xFFFFF;
            int t1 = payload[beg + j0 + 2 + h] & 0xFFFFF;
            int t2 = payload[beg + j0 + 4 + h] & 0xFFFFF;
            int t3 = payload[beg + j0 + 6 + h] & 0xFFFFF;
            float x0 = __uint_as_float((unsigned)xh[((unsigned)t0 << 5) + o] << 16);
            float x1 = __uint_as_float((unsigned)xh[((unsigned)t1 << 5) + o] << 16);
            float x2 = __uint_as_float((unsigned)xh[((unsigned)t2 << 5) + o] << 16);
            float x3 = __uint_as_float((unsigned)xh[((unsigned)t3 << 5) + o] << 16);
            w0 = fmaf(b0, x0, w0); w1 = fmaf(b1, x1, w1);
            w2 = fmaf(b2, x2, w2); w3 = fmaf(b3, x3, w3);
        }
        float vv = (w0 + w1) + (w2 + w3);
        vv += __shfl_xor(vv, 32, 64);
        if (h == 0) agg[(size_t)d * OUT + o] += vv;
        return;
    }

    // --- generic fallback (cnt > 64) ---
    float sex[8] = {0.f,0.f,0.f,0.f,0.f,0.f,0.f,0.f};
    for (int i = beg + lane; i < end; i += 64) {
        int sr = payload[i];
        int r = sr & 7;
        float pi = pid[0];
        #pragma unroll
        for (int k = 1; k < 8; k++) pi = (r == k) ? pid[k] : pi;
        float a = pi + p_j[sr];
        a = (a >= 0.f) ? a : NEG_SLOPE * a;
        float ev = __expf(a);
        #pragma unroll
        for (int k = 0; k < 8; k++) sex[k] += (r == k) ? ev : 0.f;
    }
    #pragma unroll
    for (int k = 0; k < 8; k++) {
        #pragma unroll
        for (int m = 1; m <= 32; m <<= 1) sex[k] += __shfl_xor(sex[k], m, 64);
    }
    float v0 = 0.f;
    for (int c = beg; c < end; c += 64) {
        int i = c + lane;
        int sr = 0; float al = 0.f;
        if (i < end) {
            sr = payload[i];
            int r = sr & 7;
            float pi = pid[0];
            #pragma unroll
            for (int k = 1; k < 8; k++) pi = (r == k) ? pid[k] : pi;
            float a = pi + p_j[sr];
            a = (a >= 0.f) ? a : NEG_SLOPE * a;
            float ev = __expf(a);
            float de = sex[0];
            #pragma unroll
            for (int k = 1; k < 8; k++) de = (r == k) ? sex[k] : de;
            al = ev / (de + 1e-16f);
        }
        int m = min(64, end - c);
        for (int j0 = 0; j0 < m; j0 += 2) {
            int e0 = j0 + h;
            float a0 = __shfl(al, e0, 64); int s0 = __shfl(sr, e0, 64);
            if (e0 < m) {
                float xv = __uint_as_float((unsigned)xh[((unsigned)s0 << 5) + o] << 16);
                v0 = fmaf(a0, xv, v0);
            }
        }
    }
    float vv = v0;
    vv += __shfl_xor(vv, 32, 64);
    if (h == 0) agg[(size_t)d * OUT + o] += vv;
}

// -------- K5: one thread per item; weights float4 in LDS; k-outer/j-inner unrolled.
__global__ __launch_bounds__(64, 1) void k5_mlp(const int* __restrict__ users,
                                                const int* __restrict__ bundles,
                                                const float* __restrict__ agg,
                                                const float* __restrict__ W1,
                                                const float* __restrict__ b1,
                                                const float* __restrict__ W2,
                                                const float* __restrict__ b2,
                                                const float* __restrict__ W3,
                                                const float* __restrict__ b3,
                                                const float* __restrict__ Wo,
                                                const float* __restrict__ bo,
                                                float* __restrict__ out) {
    __shared__ float4 W1s[2 * OUT * H1 / 4];   // [k*16+j4]
    __shared__ float4 W2s[H1 * H2 / 4];        // [k*8+j4]
    __shared__ float4 W3s[H2 * H3 / 4];        // [k*4+j4]
    __shared__ float b1s[H1], b2s[H2], b3s[H3], Wos[H3];
    __shared__ float bos;
    const int t = threadIdx.x;

    const float4* W14 = (const float4*)W1;
    const float4* W24 = (const float4*)W2;
    const float4* W34 = (const float4*)W3;
    for (int i = t; i < 1024; i += 64) W1s[i] = W14[i];
    for (int i = t; i < 512; i += 64) W2s[i] = W24[i];
    for (int i = t; i < 128; i += 64) W3s[i] = W34[i];
    b1s[t] = b1[t];
    if (t < H2) b2s[t] = b2[t];
    if (t < H3) { b3s[t] = b3[t]; Wos[t] = Wo[t]; }
    if (t == 0) bos = bo[0];
    __syncthreads();

    const int item = blockIdx.x * 64 + t;      // grid = BATCH/64 exactly
    const int u = users[item], v = bundles[item];
    const float4* av = (const float4*)agg;

    float z[64];
    #pragma unroll
    for (int c = 0; c < 8; c++) {
        float4 x = av[(size_t)u * 8 + c];
        z[4 * c + 0] = fmaxf(x.x, 0.f); z[4 * c + 1] = fmaxf(x.y, 0.f);
        z[4 * c + 2] = fmaxf(x.z, 0.f); z[4 * c + 3] = fmaxf(x.w, 0.f);
    }
    #pragma unroll
    for (int c = 0; c < 8; c++) {
        float4 x = av[(size_t)v * 8 + c];
        z[32 + 4 * c + 0] = fmaxf(x.x, 0.f); z[32 + 4 * c + 1] = fmaxf(x.y, 0.f);
        z[32 + 4 * c + 2] = fmaxf(x.z, 0.f); z[32 + 4 * c + 3] = fmaxf(x.w, 0.f);
    }

    float h1v[64];
    #pragma unroll
    for (int j = 0; j < H1; j++) h1v[j] = b1s[j];
    #pragma unroll
    for (int k = 0; k < 2 * OUT; k++) {
        float zk = z[k];
        #pragma unroll
        for (int j4 = 0; j4 < 16; j4++) {
            float4 wv = W1s[k * 16 + j4];
            h1v[4 * j4 + 0] = fmaf(zk, wv.x, h1v[4 * j4 + 0]);
            h1v[4 * j4 + 1] = fmaf(zk, wv.y, h1v[4 * j4 + 1]);
            h1v[4 * j4 + 2] = fmaf(zk, wv.z, h1v[4 * j4 + 2]);
            h1v[4 * j4 + 3] = fmaf(zk, wv.w, h1v[4 * j4 + 3]);
        }
    }
    #pragma unroll
    for (int j = 0; j < H1; j++) h1v[j] = fmaxf(h1v[j], 0.f);

    float h2v[32];
    #pragma unroll
    for (int j = 0; j < H2; j++) h2v[j] = b2s[j];
    #pragma unroll
    for (int k = 0; k < H1; k++) {
        float hk = h1v[k];
        #pragma unroll
        for (int j4 = 0; j4 < 8; j4++) {
            float4 wv = W2s[k * 8 + j4];
            h2v[4 * j4 + 0] = fmaf(hk, wv.x, h2v[4 * j4 + 0]);
            h2v[4 * j4 + 1] = fmaf(hk, wv.y, h2v[4 * j4 + 1]);
            h2v[4 * j4 + 2] = fmaf(hk, wv.z, h2v[4 * j4 + 2]);
            h2v[4 * j4 + 3] = fmaf(hk, wv.w, h2v[4 * j4 + 3]);
        }
    }
    #pragma unroll
    for (int j = 0; j < H2; j++) h2v[j] = fmaxf(h2v[j], 0.f);

    float h3v[16];
    #pragma unroll
    for (int j = 0; j < H3; j++) h3v[j] = b3s[j];
    #pragma unroll
    for (int k = 0; k < H2; k++) {
        float hk = h2v[k];
        #pragma unroll
        for (int j4 = 0; j4 < 4; j4++) {
            float4 wv = W3s[k * 4 + j4];
            h3v[4 * j4 + 0] = fmaf(hk, wv.x, h3v[4 * j4 + 0]);
            h3v[4 * j4 + 1] = fmaf(hk, wv.y, h3v[4 * j4 + 1]);
            h3v[4 * j4 + 2] = fmaf(hk, wv.z, h3v[4 * j4 + 2]);
            h3v[4 * j4 + 3] = fmaf(hk, wv.w, h3v[4 * j4 + 3]);
        }
    }
    #pragma unroll
    for (int j = 0; j < H3; j++) h3v[j] = fmaxf(h3v[j], 0.f);

    float acc = bos;
    #pragma unroll
    for (int k = 0; k < H3; k++) acc = fmaf(h3v[k], Wos[k], acc);
    out[item] = acc;
}

extern "C" void kernel_launch(void* const* d_in, const int* in_sizes, int n_in,
                              void* d_out, int out_size, void* d_ws, size_t ws_size,
                              hipStream_t stream) {
    (void)in_sizes; (void)n_in; (void)out_size; (void)ws_size;
    // d_in[0] (x_ids) is arange(N_NODE) by construction -> not needed.
    const int*   eidx   = (const int*)d_in[1];     // (2,E): row0=src, row1=dst
    const int*   etype  = (const int*)d_in[2];
    const int*   users  = (const int*)d_in[3];
    const int*   bund   = (const int*)d_in[4];
    const float* emb    = (const float*)d_in[5];
    const float* basis  = (const float*)d_in[6];
    const float* weight = (const float*)d_in[7];
    const float* att    = (const float*)d_in[8];
    const float* root   = (const float*)d_in[9];
    const float* bias   = (const float*)d_in[10];
    const float* W1 = (const float*)d_in[11]; const float* b1 = (const float*)d_in[12];
    const float* W2 = (const float*)d_in[13]; const float* b2 = (const float*)d_in[14];
    const float* W3 = (const float*)d_in[15]; const float* b3 = (const float*)d_in[16];
    const float* Wo = (const float*)d_in[17]; const float* bo = (const float*)d_in[18];
    float* out = (float*)d_out;

    const int* src = eidx;
    const int* dst = eidx + E_EDGE;

    // workspace layout (4-byte elements unless noted)
    float* ws       = (float*)d_ws;
    float* w        = ws;                                   //      8,192
    float* wa       = w + N_REL * EMB * OUT;                //        512
    unsigned short* xh = (unsigned short*)(wa + 512);       // 25.6M ushort (bf16)
    float* p_i      = (float*)(xh + (size_t)N_NODE * 256);  //    800,000
    float* p_j      = p_i + N_NODE * N_REL;                 //    800,000
    float* agg      = p_j + N_NODE * N_REL;                 //  3,200,000
    int*   payload  = (int*)(agg + (long)N_NODE * OUT);     //  2,001,920 (padded slabs)
    int*   begp     = payload + NBKT * BCAP;                //    100,000
    int*   endp     = begp + N_NODE;                        //    100,000
    unsigned* bcnt  = (unsigned*)(endp + N_NODE);           //        512
    // part (8 MB) aliases agg (12.8 MB): consumed by k_sort before k_pi writes agg
    unsigned* part  = (unsigned*)agg;

    k0f<<<1, 256, 0, stream>>>(weight, basis, att, w, wa, bcnt);
    k_part<<<(E_EDGE + PCH - 1) / PCH, 256, 0, stream>>>(src, dst, etype, bcnt, part);
    k_sort<<<NBKT, 256, 0, stream>>>(bcnt, part, payload, begp, endp);
    k1_transform<<<2048, 256, 0, stream>>>(emb, w, xh);
    k_pi<<<(N_NODE * OUT) / 256, 256, 0, stream>>>(emb, wa, root, bias,
                                                   p_i, p_j, agg);
    k_agg<<<12500, 256, 0, stream>>>(begp, endp, payload, p_i, p_j, xh, agg,
                                     0, 50000);
    k_agg<<<12500, 256, 0, stream>>>(begp, endp, payload, p_i, p_j, xh, agg,
                                     50000, 100000);
    k5_mlp<<<BATCH / 64, 64, 0, stream>>>(users, bund, agg, W1, b1, W2, b2, W3, b3,
                                          Wo, bo, out);
}

// Round 17
// 336.908 us; speedup vs baseline: 1.0390x; 1.0390x over previous
//
#include <hip/hip_runtime.h>
#include <hip/hip_bf16.h>

#define N_NODE 100000
#define N_REL  8
#define EMB    32
#define OUT    32
#define N_BASIS 30
#define E_EDGE 1600000
#define BATCH  16384
#define H1 64
#define H2 32
#define H3 16
#define NEG_SLOPE 0.2f

#define BSH   8             // bucket = dst >> 8 (256 nodes/bucket)
#define NBKT  391           // ceil(100000/256)
#define BCAP  5120          // per-bucket slot capacity (mean 4092, +16 sigma)
#define PCH   2048          // edges per k_part block; 782 blocks (3/CU)

#define K5T   128           // k5 threads/block; grid = BATCH/K5T = 128

// x_ids = arange(N_NODE) by construction -> emb read directly (affine addresses).

// -------- K0f: w = weight@basis (also to LDS), wa = w·att halves, zero bcnt. 1 block.
__global__ __launch_bounds__(256) void k0f(const float* __restrict__ weight,
                                           const float* __restrict__ basis,
                                           const float* __restrict__ att,
                                           float* __restrict__ w,
                                           float* __restrict__ wa,
                                           unsigned* __restrict__ bcnt) {
    __shared__ float wl[N_REL * EMB * OUT];    // 32 KB
    int t = threadIdx.x;
    for (int i = t; i < N_REL * EMB * OUT; i += 256) {
        int r = i >> 10, fo = i & 1023;
        float acc = 0.f;
        #pragma unroll
        for (int b = 0; b < N_BASIS; b++)
            acc = fmaf(weight[r * N_BASIS + b], basis[b * (EMB * OUT) + fo], acc);
        wl[i] = acc;
        w[i] = acc;
    }
    __syncthreads();
    for (int i = t; i < 512; i += 256) {       // wa[which][r][f]
        int which = i >> 8, rf = i & 255, r = rf >> 5, f = rf & 31;
        const float* wrow = wl + (r * 32 + f) * 32;
        const float* arow = att + r * 64 + which * 32;
        float acc = 0.f;
        #pragma unroll
        for (int o = 0; o < 32; o++) acc = fmaf(wrow[o], arow[o], acc);
        wa[i] = acc;
    }
    for (int i = t; i < NBKT; i += 256) bcnt[i] = 0;
}

// -------- K1: xh = x@w in BF16. wc pinned in VGPRs via empty asm.
__global__ __launch_bounds__(256, 4) void k1_transform(const float* __restrict__ emb,
                                                       const float* __restrict__ w,
                                                       unsigned short* __restrict__ xh) {
    const int t = threadIdx.x;
    const int o = t & 31;
    const int r = t >> 5;

    float wc[EMB];
    #pragma unroll
    for (int f = 0; f < EMB; f++) wc[f] = w[(r * EMB + f) * OUT + o];
    #pragma unroll
    for (int f = 0; f < EMB; f++) asm volatile("" : "+v"(wc[f]));  // pin: no remat

    for (int n0 = blockIdx.x * 4; n0 < N_NODE; n0 += gridDim.x * 4) {
        const float* __restrict__ x0 = emb + (size_t)(n0 + 0) * EMB;
        const float* __restrict__ x1 = emb + (size_t)(n0 + 1) * EMB;
        const float* __restrict__ x2 = emb + (size_t)(n0 + 2) * EMB;
        const float* __restrict__ x3 = emb + (size_t)(n0 + 3) * EMB;

        float a0 = 0.f, a1 = 0.f, a2 = 0.f, a3 = 0.f;
        #pragma unroll
        for (int f = 0; f < EMB; f++) {
            a0 = fmaf(x0[f], wc[f], a0);
            a1 = fmaf(x1[f], wc[f], a1);
            a2 = fmaf(x2[f], wc[f], a2);
            a3 = fmaf(x3[f], wc[f], a3);
        }
        __hip_bfloat16 b0 = __float2bfloat16(a0);
        __hip_bfloat16 b1 = __float2bfloat16(a1);
        __hip_bfloat16 b2 = __float2bfloat16(a2);
        __hip_bfloat16 b3 = __float2bfloat16(a3);
        xh[(size_t)(n0 + 0) * 256 + t] = *(unsigned short*)&b0;
        xh[(size_t)(n0 + 1) * 256 + t] = *(unsigned short*)&b1;
        xh[(size_t)(n0 + 2) * 256 + t] = *(unsigned short*)&b2;
        xh[(size_t)(n0 + 3) * 256 + t] = *(unsigned short*)&b3;
    }
}

// -------- k_pi: fused agg-init + p_i/p_j. Thread per (n,o); emb row direct.
__global__ __launch_bounds__(256) void k_pi(const float* __restrict__ emb,
                                            const float* __restrict__ wa,
                                            const float* __restrict__ root,
                                            const float* __restrict__ bias,
                                            float* __restrict__ p_i,
                                            float* __restrict__ p_j,
                                            float* __restrict__ agg) {
    __shared__ float rs[EMB * OUT];            // [f*32+o]
    __shared__ float bs[OUT];
    __shared__ float wis[256], wjs[256];       // [f*8+r]
    int t = threadIdx.x;
    for (int i = t; i < EMB * OUT; i += 256) rs[i] = root[i];
    if (t < OUT) bs[t] = bias[t];
    for (int i = t; i < 512; i += 256) {
        int which = i >> 8, r = (i >> 5) & 7, f = i & 31;
        float v = wa[i];
        if (which == 0) wis[f * 8 + r] = v; else wjs[f * 8 + r] = v;
    }
    __syncthreads();
    int tg = blockIdx.x * 256 + t;             // grid*256 == 3,200,000 exactly
    int n = tg >> 5, o = tg & 31;
    const float4* xr4 = (const float4*)(emb + (size_t)n * EMB);
    float xf[EMB];
    #pragma unroll
    for (int c = 0; c < 8; c++) {
        float4 xv = xr4[c];
        xf[4 * c + 0] = xv.x; xf[4 * c + 1] = xv.y;
        xf[4 * c + 2] = xv.z; xf[4 * c + 3] = xv.w;
    }
    float a = bs[o];
    #pragma unroll
    for (int f = 0; f < EMB; f++) a = fmaf(xf[f], rs[f * 32 + o], a);
    agg[tg] = a;
    if (o < N_REL) {                           // lanes 0-7 / 32-39 also emit p for r=o
        float ai = 0.f, aj = 0.f;
        #pragma unroll
        for (int f = 0; f < EMB; f++) {
            ai = fmaf(xf[f], wis[f * 8 + o], ai);
            aj = fmaf(xf[f], wjs[f * 8 + o], aj);
        }
        p_i[n * N_REL + o] = ai;
        p_j[n * N_REL + o] = aj;
    }
}

// -------- k_part: vectorized single-pass edge loads (int4), bucket-major staging.
__global__ __launch_bounds__(256) void k_part(const int* __restrict__ src,
                                              const int* __restrict__ dst,
                                              const int* __restrict__ et,
                                              unsigned* __restrict__ bcnt,
                                              unsigned* __restrict__ part) {
    __shared__ unsigned long long stage[PCH];            // 16 KB
    __shared__ unsigned hist[NBKT], lbase[NBKT], lcur[NBKT], gbase[NBKT];
    __shared__ unsigned sc[256];
    int t = threadIdx.x;
    for (int i = t; i < NBKT; i += 256) hist[i] = 0;
    __syncthreads();
    int beg = blockIdx.x * PCH, end = min(beg + PCH, E_EDGE);
    int n = end - beg;                  // multiple of 4
    int ng = n >> 2;
    int g0 = t, g1 = t + 256;
    bool has0 = g0 < ng, has1 = g1 < ng;
    int4 s0v = {}, d0v = {}, e0v = {}, s1v = {}, d1v = {}, e1v = {};
    if (has0) {
        s0v = *(const int4*)&src[beg + 4 * g0];
        d0v = *(const int4*)&dst[beg + 4 * g0];
        e0v = *(const int4*)&et[beg + 4 * g0];
    }
    if (has1) {
        s1v = *(const int4*)&src[beg + 4 * g1];
        d1v = *(const int4*)&dst[beg + 4 * g1];
        e1v = *(const int4*)&et[beg + 4 * g1];
    }
    if (has0) {
        atomicAdd(&hist[(unsigned)d0v.x >> BSH], 1u);
        atomicAdd(&hist[(unsigned)d0v.y >> BSH], 1u);
        atomicAdd(&hist[(unsigned)d0v.z >> BSH], 1u);
        atomicAdd(&hist[(unsigned)d0v.w >> BSH], 1u);
    }
    if (has1) {
        atomicAdd(&hist[(unsigned)d1v.x >> BSH], 1u);
        atomicAdd(&hist[(unsigned)d1v.y >> BSH], 1u);
        atomicAdd(&hist[(unsigned)d1v.z >> BSH], 1u);
        atomicAdd(&hist[(unsigned)d1v.w >> BSH], 1u);
    }
    __syncthreads();
    unsigned v0 = (2 * t < NBKT) ? hist[2 * t] : 0u;
    unsigned v1 = (2 * t + 1 < NBKT) ? hist[2 * t + 1] : 0u;
    unsigned s = v0 + v1;
    sc[t] = s;
    __syncthreads();
    for (int off = 1; off < 256; off <<= 1) {
        unsigned y = (t >= off) ? sc[t - off] : 0u;
        __syncthreads();
        sc[t] += y;
        __syncthreads();
    }
    unsigned ex = sc[t] - s;
    if (2 * t < NBKT)     { lbase[2 * t] = ex;          lcur[2 * t] = ex; }
    if (2 * t + 1 < NBKT) { lbase[2 * t + 1] = ex + v0; lcur[2 * t + 1] = ex + v0; }
    __syncthreads();
    #define K_PART_STAGE(dd, ss, ee) do {                                   \
        unsigned b_ = (unsigned)(dd) >> BSH;                                \
        unsigned ent_ = ((unsigned)((dd) & 255) << 20)                      \
                      | ((unsigned)(ss) << 3) | (unsigned)(ee);             \
        unsigned pos_ = atomicAdd(&lcur[b_], 1u);                           \
        stage[pos_] = ((unsigned long long)b_ << 32) | ent_; } while (0)
    if (has0) {
        K_PART_STAGE(d0v.x, s0v.x, e0v.x);
        K_PART_STAGE(d0v.y, s0v.y, e0v.y);
        K_PART_STAGE(d0v.z, s0v.z, e0v.z);
        K_PART_STAGE(d0v.w, s0v.w, e0v.w);
    }
    if (has1) {
        K_PART_STAGE(d1v.x, s1v.x, e1v.x);
        K_PART_STAGE(d1v.y, s1v.y, e1v.y);
        K_PART_STAGE(d1v.z, s1v.z, e1v.z);
        K_PART_STAGE(d1v.w, s1v.w, e1v.w);
    }
    #undef K_PART_STAGE
    __syncthreads();
    for (int i = t; i < NBKT; i += 256)
        if (hist[i]) gbase[i] = atomicAdd(&bcnt[i], hist[i]);
    __syncthreads();
    for (int i = t; i < n; i += 256) {
        unsigned long long s64 = stage[i];
        unsigned b = (unsigned)(s64 >> 32);
        unsigned ent = (unsigned)s64;
        part[b * BCAP + gbase[b] + (i - lbase[b])] = ent;   // contiguous runs
    }
}

// -------- k_sort: block per bucket (391); counting sort by dst-low (256 bins).
__global__ __launch_bounds__(256) void k_sort(const unsigned* __restrict__ bcnt,
                                              const unsigned* __restrict__ part,
                                              int* __restrict__ payload,
                                              int* __restrict__ begp,
                                              int* __restrict__ endp) {
    __shared__ unsigned ent[BCAP];             // 20 KB
    __shared__ unsigned ent2[BCAP];            // 20 KB
    __shared__ unsigned hist[256], dbase[256], dcur[256];
    __shared__ unsigned sc[256];
    int t = threadIdx.x;
    int b = blockIdx.x;
    unsigned s0 = (unsigned)b * BCAP;          // 4-aligned
    int n = (int)bcnt[b];
    if (n > BCAP) n = BCAP;
    hist[t] = 0;
    __syncthreads();
    int n4 = n & ~3;
    for (int i = 4 * t; i < n4; i += 1024) {
        uint4 e4 = *(const uint4*)&part[s0 + i];
        ent[i + 0] = e4.x; atomicAdd(&hist[e4.x >> 20], 1u);
        ent[i + 1] = e4.y; atomicAdd(&hist[e4.y >> 20], 1u);
        ent[i + 2] = e4.z; atomicAdd(&hist[e4.z >> 20], 1u);
        ent[i + 3] = e4.w; atomicAdd(&hist[e4.w >> 20], 1u);
    }
    for (int i = n4 + t; i < n; i += 256) {
        unsigned e = part[s0 + i];
        ent[i] = e;
        atomicAdd(&hist[e >> 20], 1u);
    }
    __syncthreads();
    unsigned v = hist[t];
    sc[t] = v;
    __syncthreads();
    for (int off = 1; off < 256; off <<= 1) {
        unsigned y = (t >= off) ? sc[t - off] : 0u;
        __syncthreads();
        sc[t] += y;
        __syncthreads();
    }
    unsigned ex = sc[t] - v;
    dbase[t] = ex;
    dcur[t] = ex;
    __syncthreads();
    int d = (b << BSH) + t;
    if (d < N_NODE) {
        begp[d] = (int)(s0 + dbase[t]);
        endp[d] = (int)(s0 + dbase[t] + hist[t]);
    }
    for (int i = t; i < n; i += 256) {
        unsigned e = ent[i];
        unsigned pos = atomicAdd(&dcur[e >> 20], 1u);
        ent2[pos] = e & 0xFFFFFu;                // sr = (src<<3)|rel
    }
    __syncthreads();
    for (int i = 4 * t; i < n4; i += 1024) {
        uint4 o4 = { ent2[i + 0], ent2[i + 1], ent2[i + 2], ent2[i + 3] };
        *(uint4*)&payload[s0 + i] = o4;
    }
    for (int i = n4 + t; i < n; i += 256) payload[s0 + i] = (int)ent2[i];
}

// ------------- k_agg: wave per dst, over d-range [d0,d1). bf16 xh rows.
__global__ __launch_bounds__(256) void k_agg(const int* __restrict__ begp,
                                             const int* __restrict__ endp,
                                             const int* __restrict__ payload,
                                             const float* __restrict__ p_i,
                                             const float* __restrict__ p_j,
                                             const unsigned short* __restrict__ xh,
                                             float* __restrict__ agg,
                                             int d0, int d1) {
    int d = d0 + blockIdx.x * 4 + (threadIdx.x >> 6);
    if (d >= d1) return;
    const int lane = threadIdx.x & 63;
    const int h = lane >> 5;          // half-wave id
    const int o = lane & 31;          // output component
    const int beg = begp[d], end = endp[d];
    const int cnt = end - beg;
    if (cnt == 0) return;

    float pid[8];                     // d wave-uniform -> scalar loads
    #pragma unroll
    for (int k = 0; k < 8; k++) pid[k] = p_i[(d << 3) | k];

    if (cnt <= 64) {
        int sr = 0, r = 0; float ev = 0.f;
        if (lane < cnt) {
            sr = payload[beg + lane];
            r = sr & 7;
            float pi = pid[0];
            #pragma unroll
            for (int k = 1; k < 8; k++) pi = (r == k) ? pid[k] : pi;
            float a = pi + p_j[sr];
            a = (a >= 0.f) ? a : NEG_SLOPE * a;
            ev = __expf(a);
        }
        float sex[8];
        #pragma unroll
        for (int k = 0; k < 8; k++) sex[k] = (r == k) ? ev : 0.f;
        #pragma unroll
        for (int k = 0; k < 8; k++) {
            #pragma unroll
            for (int m = 1; m <= 32; m <<= 1) sex[k] += __shfl_xor(sex[k], m, 64);
        }
        float de = sex[0];
        #pragma unroll
        for (int k = 1; k < 8; k++) de = (r == k) ? sex[k] : de;
        float al = ev / (de + 1e-16f);           // inactive lanes: al = 0

        float w0 = 0.f, w1 = 0.f, w2 = 0.f, w3 = 0.f;
        for (int j0 = 0; j0 < cnt; j0 += 8) {
            float b0 = __shfl(al, j0 + h,     64);
            float b1 = __shfl(al, j0 + 2 + h, 64);
            float b2 = __shfl(al, j0 + 4 + h, 64);
            float b3 = __shfl(al, j0 + 6 + h, 64);
            int t0 = payload[beg + j0 + h]     & 0xFFFFF;
            int t1 = payload[beg + j0 + 2 + h] & 0xFFFFF;
            int t2 = payload[beg + j0 + 4 + h] & 0xFFFFF;
            int t3 = payload[beg + j0 + 6 + h] & 0xFFFFF;
            float x0 = __uint_as_float((unsigned)xh[((unsigned)t0 << 5) + o] << 16);
            float x1 = __uint_as_float((unsigned)xh[((unsigned)t1 << 5) + o] << 16);
            float x2 = __uint_as_float((unsigned)xh[((unsigned)t2 << 5) + o] << 16);
            float x3 = __uint_as_float((unsigned)xh[((unsigned)t3 << 5) + o] << 16);
            w0 = fmaf(b0, x0, w0); w1 = fmaf(b1, x1, w1);
            w2 = fmaf(b2, x2, w2); w3 = fmaf(b3, x3, w3);
        }
        float vv = (w0 + w1) + (w2 + w3);
        vv += __shfl_xor(vv, 32, 64);
        if (h == 0) agg[(size_t)d * OUT + o] += vv;
        return;
    }

    // --- generic fallback (cnt > 64) ---
    float sex[8] = {0.f,0.f,0.f,0.f,0.f,0.f,0.f,0.f};
    for (int i = beg + lane; i < end; i += 64) {
        int sr = payload[i];
        int r = sr & 7;
        float pi = pid[0];
        #pragma unroll
        for (int k = 1; k < 8; k++) pi = (r == k) ? pid[k] : pi;
        float a = pi + p_j[sr];
        a = (a >= 0.f) ? a : NEG_SLOPE * a;
        float ev = __expf(a);
        #pragma unroll
        for (int k = 0; k < 8; k++) sex[k] += (r == k) ? ev : 0.f;
    }
    #pragma unroll
    for (int k = 0; k < 8; k++) {
        #pragma unroll
        for (int m = 1; m <= 32; m <<= 1) sex[k] += __shfl_xor(sex[k], m, 64);
    }
    float v0 = 0.f;
    for (int c = beg; c < end; c += 64) {
        int i = c + lane;
        int sr = 0; float al = 0.f;
        if (i < end) {
            sr = payload[i];
            int r = sr & 7;
            float pi = pid[0];
            #pragma unroll
            for (int k = 1; k < 8; k++) pi = (r == k) ? pid[k] : pi;
            float a = pi + p_j[sr];
            a = (a >= 0.f) ? a : NEG_SLOPE * a;
            float ev = __expf(a);
            float de = sex[0];
            #pragma unroll
            for (int k = 1; k < 8; k++) de = (r == k) ? sex[k] : de;
            al = ev / (de + 1e-16f);
        }
        int m = min(64, end - c);
        for (int j0 = 0; j0 < m; j0 += 2) {
            int e0 = j0 + h;
            float a0 = __shfl(al, e0, 64); int s0 = __shfl(sr, e0, 64);
            if (e0 < m) {
                float xv = __uint_as_float((unsigned)xh[((unsigned)s0 << 5) + o] << 16);
                v0 = fmaf(a0, xv, v0);
            }
        }
    }
    float vv = v0;
    vv += __shfl_xor(vv, 32, 64);
    if (h == 0) agg[(size_t)d * OUT + o] += vv;
}

// -------- K5: one thread per item; activations in LDS (padded rows, (t+k)%32 banks =
// 2-way = free), NOT registers (VGPR_Count=108 + scratch spill was the 122us cause).
// Per-thread rows are private -> no barriers between layers. Weights = float4 LDS
// broadcasts (wave-uniform ds_read_b128). ~40 VGPRs, no spill possible.
__global__ __launch_bounds__(K5T, 1) void k5_mlp(const int* __restrict__ users,
                                                 const int* __restrict__ bundles,
                                                 const float* __restrict__ agg,
                                                 const float* __restrict__ W1,
                                                 const float* __restrict__ b1,
                                                 const float* __restrict__ W2,
                                                 const float* __restrict__ b2,
                                                 const float* __restrict__ W3,
                                                 const float* __restrict__ b3,
                                                 const float* __restrict__ Wo,
                                                 const float* __restrict__ bo,
                                                 float* __restrict__ out) {
    __shared__ float4 W1s[2 * OUT * H1 / 4];   // [k*16+j4] 16 KB
    __shared__ float4 W2s[H1 * H2 / 4];        // [k*8+j4]   8 KB
    __shared__ float4 W3s[H2 * H3 / 4];        // [k*4+j4]   2 KB
    __shared__ float b1s[H1], b2s[H2], b3s[H3], Wos[H3];
    __shared__ float bos;
    __shared__ float zs[K5T * 65];             // 33.3 KB: z row per thread
    __shared__ float h1s[K5T * 65];            // 33.3 KB: h1 row per thread
    const int t = threadIdx.x;

    const float4* W14 = (const float4*)W1;
    const float4* W24 = (const float4*)W2;
    const float4* W34 = (const float4*)W3;
    for (int i = t; i < 1024; i += K5T) W1s[i] = W14[i];
    for (int i = t; i < 512; i += K5T) W2s[i] = W24[i];
    for (int i = t; i < 128; i += K5T) W3s[i] = W34[i];
    if (t < H1) b1s[t] = b1[t];
    if (t < H2) b2s[t] = b2[t];
    if (t < H3) { b3s[t] = b3[t]; Wos[t] = Wo[t]; }
    if (t == 0) bos = bo[0];

    const int item = blockIdx.x * K5T + t;     // grid = BATCH/K5T exactly
    const int u = users[item], v = bundles[item];
    const float4* av = (const float4*)agg;
    float* zrow = &zs[t * 65];
    float* h1row = &h1s[t * 65];

    #pragma unroll
    for (int c = 0; c < 8; c++) {
        float4 x = av[(size_t)u * 8 + c];
        zrow[4 * c + 0] = fmaxf(x.x, 0.f); zrow[4 * c + 1] = fmaxf(x.y, 0.f);
        zrow[4 * c + 2] = fmaxf(x.z, 0.f); zrow[4 * c + 3] = fmaxf(x.w, 0.f);
    }
    #pragma unroll
    for (int c = 0; c < 8; c++) {
        float4 x = av[(size_t)v * 8 + c];
        zrow[32 + 4 * c + 0] = fmaxf(x.x, 0.f); zrow[32 + 4 * c + 1] = fmaxf(x.y, 0.f);
        zrow[32 + 4 * c + 2] = fmaxf(x.z, 0.f); zrow[32 + 4 * c + 3] = fmaxf(x.w, 0.f);
    }
    __syncthreads();   // weights staged (z rows are thread-private)

    // layer 1: 64 -> 64, j4-tile accumulators in regs, z from private LDS row
    #pragma unroll 4
    for (int j4 = 0; j4 < 16; j4++) {
        float a0 = b1s[4 * j4 + 0], a1 = b1s[4 * j4 + 1];
        float a2 = b1s[4 * j4 + 2], a3 = b1s[4 * j4 + 3];
        #pragma unroll 16
        for (int k = 0; k < 2 * OUT; k++) {
            float zk = zrow[k];
            float4 wv = W1s[k * 16 + j4];
            a0 = fmaf(zk, wv.x, a0); a1 = fmaf(zk, wv.y, a1);
            a2 = fmaf(zk, wv.z, a2); a3 = fmaf(zk, wv.w, a3);
        }
        h1row[4 * j4 + 0] = fmaxf(a0, 0.f); h1row[4 * j4 + 1] = fmaxf(a1, 0.f);
        h1row[4 * j4 + 2] = fmaxf(a2, 0.f); h1row[4 * j4 + 3] = fmaxf(a3, 0.f);
    }

    // layer 2: 64 -> 32, result overwrites zrow (z dead after layer 1)
    #pragma unroll 4
    for (int j4 = 0; j4 < 8; j4++) {
        float a0 = b2s[4 * j4 + 0], a1 = b2s[4 * j4 + 1];
        float a2 = b2s[4 * j4 + 2], a3 = b2s[4 * j4 + 3];
        #pragma unroll 16
        for (int k = 0; k < H1; k++) {
            float hk = h1row[k];
            float4 wv = W2s[k * 8 + j4];
            a0 = fmaf(hk, wv.x, a0); a1 = fmaf(hk, wv.y, a1);
            a2 = fmaf(hk, wv.z, a2); a3 = fmaf(hk, wv.w, a3);
        }
        zrow[4 * j4 + 0] = fmaxf(a0, 0.f); zrow[4 * j4 + 1] = fmaxf(a1, 0.f);
        zrow[4 * j4 + 2] = fmaxf(a2, 0.f); zrow[4 * j4 + 3] = fmaxf(a3, 0.f);
    }

    // layer 3: 32 -> 16, into registers
    float h3v[16];
    #pragma unroll
    for (int j4 = 0; j4 < 4; j4++) {
        float a0 = b3s[4 * j4 + 0], a1 = b3s[4 * j4 + 1];
        float a2 = b3s[4 * j4 + 2], a3 = b3s[4 * j4 + 3];
        #pragma unroll 16
        for (int k = 0; k < H2; k++) {
            float hk = zrow[k];
            float4 wv = W3s[k * 4 + j4];
            a0 = fmaf(hk, wv.x, a0); a1 = fmaf(hk, wv.y, a1);
            a2 = fmaf(hk, wv.z, a2); a3 = fmaf(hk, wv.w, a3);
        }
        h3v[4 * j4 + 0] = fmaxf(a0, 0.f); h3v[4 * j4 + 1] = fmaxf(a1, 0.f);
        h3v[4 * j4 + 2] = fmaxf(a2, 0.f); h3v[4 * j4 + 3] = fmaxf(a3, 0.f);
    }

    float acc = bos;
    #pragma unroll
    for (int k = 0; k < H3; k++) acc = fmaf(h3v[k], Wos[k], acc);
    out[item] = acc;
}

extern "C" void kernel_launch(void* const* d_in, const int* in_sizes, int n_in,
                              void* d_out, int out_size, void* d_ws, size_t ws_size,
                              hipStream_t stream) {
    (void)in_sizes; (void)n_in; (void)out_size; (void)ws_size;
    // d_in[0] (x_ids) is arange(N_NODE) by construction -> not needed.
    const int*   eidx   = (const int*)d_in[1];     // (2,E): row0=src, row1=dst
    const int*   etype  = (const int*)d_in[2];
    const int*   users  = (const int*)d_in[3];
    const int*   bund   = (const int*)d_in[4];
    const float* emb    = (const float*)d_in[5];
    const float* basis  = (const float*)d_in[6];
    const float* weight = (const float*)d_in[7];
    const float* att    = (const float*)d_in[8];
    const float* root   = (const float*)d_in[9];
    const float* bias   = (const float*)d_in[10];
    const float* W1 = (const float*)d_in[11]; const float* b1 = (const float*)d_in[12];
    const float* W2 = (const float*)d_in[13]; const float* b2 = (const float*)d_in[14];
    const float* W3 = (const float*)d_in[15]; const float* b3 = (const float*)d_in[16];
    const float* Wo = (const float*)d_in[17]; const float* bo = (const float*)d_in[18];
    float* out = (float*)d_out;

    const int* src = eidx;
    const int* dst = eidx + E_EDGE;

    // workspace layout (4-byte elements unless noted)
    float* ws       = (float*)d_ws;
    float* w        = ws;                                   //      8,192
    float* wa       = w + N_REL * EMB * OUT;                //        512
    unsigned short* xh = (unsigned short*)(wa + 512);       // 25.6M ushort (bf16)
    float* p_i      = (float*)(xh + (size_t)N_NODE * 256);  //    800,000
    float* p_j      = p_i + N_NODE * N_REL;                 //    800,000
    float* agg      = p_j + N_NODE * N_REL;                 //  3,200,000
    int*   payload  = (int*)(agg + (long)N_NODE * OUT);     //  2,001,920 (padded slabs)
    int*   begp     = payload + NBKT * BCAP;                //    100,000
    int*   endp     = begp + N_NODE;                        //    100,000
    unsigned* bcnt  = (unsigned*)(endp + N_NODE);           //        512
    // part (8 MB) aliases agg (12.8 MB): consumed by k_sort before k_pi writes agg
    unsigned* part  = (unsigned*)agg;

    k0f<<<1, 256, 0, stream>>>(weight, basis, att, w, wa, bcnt);
    k_part<<<(E_EDGE + PCH - 1) / PCH, 256, 0, stream>>>(src, dst, etype, bcnt, part);
    k_sort<<<NBKT, 256, 0, stream>>>(bcnt, part, payload, begp, endp);
    k1_transform<<<2048, 256, 0, stream>>>(emb, w, xh);
    k_pi<<<(N_NODE * OUT) / 256, 256, 0, stream>>>(emb, wa, root, bias,
                                                   p_i, p_j, agg);
    k_agg<<<12500, 256, 0, stream>>>(begp, endp, payload, p_i, p_j, xh, agg,
                                     0, 50000);
    k_agg<<<12500, 256, 0, stream>>>(begp, endp, payload, p_i, p_j, xh, agg,
                                     50000, 100000);
    k5_mlp<<<BATCH / K5T, K5T, 0, stream>>>(users, bund, agg, W1, b1, W2, b2, W3, b3,
                                            Wo, bo, out);
}